// Round 8
// baseline (824.348 us; speedup 1.0000x reference)
//
#include <hip/hip_runtime.h>

// voltageNN: 5-layer projected LSTM (H=256, P=1) over T=1000, B=128 + MLP head.
// R8: wave-per-(layer,batch) pipeline (R3/R5 dataflow) + value-fence scheduling.
//   The compiler serializes the step into ~180 dependent instrs (~960 cyc);
//   empty volatile asm fences naming phase outputs pin the schedule into
//   regions of mutually-independent same-type ops (16 pk-fma | 16 exp2 |
//   16 add | 16 rcp | ...), so each region is issue-bound, not latency-bound.
//   Weights held as v2f -> v_pk_fma_f32 halves gate-fmaf issue.
//   Plain 5-rcp combine (R5 numerics; Montgomery's longer chain regressed R7).
//   CH=20 (fill 100 slots). MLP head fused as stage 6 (validated R7).

#define LAYERS 5
#define TT 1000
#define BATCH 128
#define CH 20            // chunk length (divides TT; <= 64)
#define NCH (TT / CH)    // 50 chunks

#define LOG2E 1.4426950408889634f

typedef float v2f __attribute__((ext_vector_type(2)));

__device__ __forceinline__ float fast_exp2(float x) {
#if __has_builtin(__builtin_amdgcn_exp2f)
  return __builtin_amdgcn_exp2f(x);
#else
  return __exp2f(x);
#endif
}
__device__ __forceinline__ float fast_rcp(float x) {
#if __has_builtin(__builtin_amdgcn_rcpf)
  return __builtin_amdgcn_rcpf(x);
#else
  return 1.0f / x;
#endif
}
__device__ __forceinline__ float fast_sigmoid(float z) {
  float e = fast_exp2(-LOG2E * z);
  return fast_rcp(1.0f + e);
}

// Value fences: order only the named defs (tiny scheduling regions), unlike
// sched_barrier(0) which pinned everything (R7 regression).
#define FENCE4(a)  asm volatile("" : "+v"(a[0]), "+v"(a[1]), "+v"(a[2]), "+v"(a[3]))
#define FENCE16(m) asm volatile("" \
  : "+v"(m[0][0]), "+v"(m[0][1]), "+v"(m[0][2]), "+v"(m[0][3]), \
    "+v"(m[1][0]), "+v"(m[1][1]), "+v"(m[1][2]), "+v"(m[1][3]), \
    "+v"(m[2][0]), "+v"(m[2][1]), "+v"(m[2][2]), "+v"(m[2][3]), \
    "+v"(m[3][0]), "+v"(m[3][1]), "+v"(m[3][2]), "+v"(m[3][3]))

template <int CTRL>
__device__ __forceinline__ float dpp_add(float v) {
  int moved = __builtin_amdgcn_update_dpp(0, __builtin_bit_cast(int, v),
                                          CTRL, 0xF, 0xF, false);
  return v + __builtin_bit_cast(float, moved);
}

// Wave64 total -> wave-uniform (readlane 63). Verified absmax==0 since R4.
__device__ __forceinline__ float wave_sum_uniform(float v) {
  v = dpp_add<0x128>(v);  // row_ror:8
  v = dpp_add<0x124>(v);  // row_ror:4
  v = dpp_add<0x122>(v);  // row_ror:2
  v = dpp_add<0x121>(v);  // row_ror:1
  v = dpp_add<0x142>(v);  // row_bcast:15
  v = dpp_add<0x143>(v);  // row_bcast:31
  return __builtin_bit_cast(float, __builtin_amdgcn_readlane(__builtin_bit_cast(int, v), 63));
}

__device__ __forceinline__ float lane_bcast(float v, int s) {
  return __builtin_bit_cast(float, __builtin_amdgcn_readlane(__builtin_bit_cast(int, v), s));
}

__global__ __launch_bounds__(64, 1) void fused_pipeline_kernel(
    const float* __restrict__ x,     // [B, T]
    const float* __restrict__ Wih,   // [L, 1024]
    const float* __restrict__ Whh,   // [L, 1024]
    const float* __restrict__ bih,   // [L, 1024]
    const float* __restrict__ bhh,   // [L, 1024]
    const float* __restrict__ Whr,   // [L, 256]
    const float* __restrict__ W1, const float* __restrict__ b1,
    const float* __restrict__ W2, const float* __restrict__ b2,
    const float* __restrict__ W3, const float* __restrict__ b3,
    const float* __restrict__ W4, const float* __restrict__ b4,
    float* __restrict__ seq,         // [L, B, T] layer outputs (workspace)
    int* __restrict__ flags,         // [L, B] chunk progress counters
    float* __restrict__ out)         // [B]
{
  const int bid  = blockIdx.x;
  const int lane = threadIdx.x & 63;

  if (bid < LAYERS * BATCH) {
    // ------------------------------------------------------------------ LSTM
    const int l = bid >> 7;
    const int b = bid & 127;

    // Weights pre-scaled into the exp2 domain (sc = -log2e for sigmoid gates
    // i,f,o; -2log2e for the tanh gate g). v2f packs units k=2p, 2p+1.
    v2f wix2[4][2], whx2[4][2], gb2[4][2];
    float whr[4], cc[4];
    const int base = l * 1024;
#pragma unroll
    for (int g = 0; g < 4; ++g) {
      const float sc = (g == 2) ? (-2.0f * LOG2E) : (-LOG2E);
#pragma unroll
      for (int p = 0; p < 2; ++p) {
        int j0 = base + g * 256 + (2 * p + 0) * 64 + lane;
        int j1 = base + g * 256 + (2 * p + 1) * 64 + lane;
        wix2[g][p] = (v2f){Wih[j0] * sc, Wih[j1] * sc};
        whx2[g][p] = (v2f){Whh[j0] * sc, Whh[j1] * sc};
        gb2[g][p]  = (v2f){(bih[j0] + bhh[j0]) * sc, (bih[j1] + bhh[j1]) * sc};
      }
    }
#pragma unroll
    for (int k = 0; k < 4; ++k) {
      whr[k] = Whr[l * 256 + k * 64 + lane];
      cc[k] = 0.0f;
    }

    const float* in  = (l == 0) ? (x + b * TT) : (seq + ((l - 1) * BATCH + b) * TT);
    float*      outp = seq + (l * BATCH + b) * TT;
    int*      my_flag = flags + l * BATCH + b;
    const int* in_flag = flags + (l - 1) * BATCH + b;  // used only when l > 0

    float h = 0.0f;
    for (int c = 0; c < NCH; ++c) {
      if (l > 0) {
        while (__hip_atomic_load(in_flag, __ATOMIC_ACQUIRE,
                                 __HIP_MEMORY_SCOPE_AGENT) <= c)
          __builtin_amdgcn_s_sleep(2);
      }
      float xv = 0.0f;
      if (lane < CH) {
        if (l == 0)
          xv = in[c * CH + lane];
        else
          xv = __hip_atomic_load(in + c * CH + lane, __ATOMIC_RELAXED,
                                 __HIP_MEMORY_SCOPE_AGENT);
      }

      float outv = 0.0f;
#pragma unroll 1
      for (int s = 0; s < CH; ++s) {
        const float xs = lane_bcast(xv, s);
        const v2f xs2 = (v2f){xs, xs};
        const v2f h2  = (v2f){h, h};

        // region 1: 16 v_pk_fma (mutually independent): arg = h*whx + (xs*wix + gb)
        float ar[4][4];
#pragma unroll
        for (int g = 0; g < 4; ++g)
#pragma unroll
          for (int p = 0; p < 2; ++p) {
            v2f t = wix2[g][p] * xs2 + gb2[g][p];   // contracts to v_pk_fma
            v2f a = whx2[g][p] * h2 + t;
            ar[g][2 * p + 0] = a.x;
            ar[g][2 * p + 1] = a.y;
          }
        FENCE16(ar);

        // region 2: 16 exp2 (independent, issue-batched)
        float E[4][4];
#pragma unroll
        for (int g = 0; g < 4; ++g)
#pragma unroll
          for (int k = 0; k < 4; ++k)
            E[g][k] = fast_exp2(ar[g][k]);
        FENCE16(E);

        // region 3: 16 adds
        float A[4][4];
#pragma unroll
        for (int g = 0; g < 4; ++g)
#pragma unroll
          for (int k = 0; k < 4; ++k)
            A[g][k] = 1.0f + E[g][k];
        FENCE16(A);

        // region 4: 16 rcps (independent, issue-batched)
        float R[4][4];
#pragma unroll
        for (int g = 0; g < 4; ++g)
#pragma unroll
          for (int k = 0; k < 4; ++k)
            R[g][k] = fast_rcp(A[g][k]);
        FENCE16(R);

        // region 5: gate mixing, 4-way zipped short chains
        float ca[4];
#pragma unroll
        for (int k = 0; k < 4; ++k) {
          float gg = fmaf(2.0f, R[2][k], -1.0f);   // tanh(pg)
          float ii = R[0][k] * gg;                 // i*g
          cc[k] = fmaf(R[1][k], cc[k], ii);        // c = f*c + i*g
          ca[k] = cc[k] * (-2.0f * LOG2E);
        }
        FENCE4(ca);

        // region 6: 4 exp2
        float e4[4];
#pragma unroll
        for (int k = 0; k < 4; ++k) e4[k] = fast_exp2(ca[k]);
        FENCE4(e4);

        // region 7: 4 adds + 4 rcps
        float r4[4];
#pragma unroll
        for (int k = 0; k < 4; ++k) r4[k] = fast_rcp(1.0f + e4[k]);
        FENCE4(r4);

        // region 8: projection partials + pairwise sum
        float rk[4];
#pragma unroll
        for (int k = 0; k < 4; ++k) {
          float tc = fmaf(2.0f, r4[k], -1.0f);     // tanh(c)
          float ow = R[3][k] * whr[k];             // o * whr
          rk[k] = ow * tc;
        }
        float r = (rk[0] + rk[1]) + (rk[2] + rk[3]);

        h = wave_sum_uniform(r);
        if (lane == s) outv = h;
      }

      if (lane < CH)
        __hip_atomic_store(outp + c * CH + lane, outv, __ATOMIC_RELAXED,
                           __HIP_MEMORY_SCOPE_AGENT);
      if (lane == 0)
        __hip_atomic_store(my_flag, c + 1, __ATOMIC_RELEASE,
                           __HIP_MEMORY_SCOPE_AGENT);
    }
  } else {
    // ------------------------------------------------------------- MLP head
    // One wave per batch. Lane owns outputs o0 = lane and o1 = 64+lane (<100).
    __shared__ float hbuf[100];
    __shared__ float hbuf2[100];

    const int b = bid - LAYERS * BATCH;
    const float* h4 = seq + (4 * BATCH + b) * TT;
    const int* f4 = flags + 4 * BATCH + b;
    const int o0 = lane;
    const int o1 = 64 + lane;
    const bool has1 = (o1 < 100);

    float acc0 = 0.0f, acc1 = 0.0f;
    for (int c = 0; c < NCH; ++c) {
      while (__hip_atomic_load(f4, __ATOMIC_ACQUIRE,
                               __HIP_MEMORY_SCOPE_AGENT) <= c)
        __builtin_amdgcn_s_sleep(8);
      float xv = 0.0f;
      if (lane < CH)
        xv = __hip_atomic_load(h4 + c * CH + lane, __ATOMIC_RELAXED,
                               __HIP_MEMORY_SCOPE_AGENT);
      const float* w0 = W1 + o0 * TT + c * CH;   // 80c-byte offset: 16B aligned
      const float* w1 = W1 + o1 * TT + c * CH;
#pragma unroll
      for (int j = 0; j < CH; j += 4) {
        float4 v0 = *(const float4*)(w0 + j);
        float x0 = lane_bcast(xv, j + 0);
        float x1 = lane_bcast(xv, j + 1);
        float x2 = lane_bcast(xv, j + 2);
        float x3 = lane_bcast(xv, j + 3);
        acc0 = fmaf(v0.x, x0, acc0);
        acc0 = fmaf(v0.y, x1, acc0);
        acc0 = fmaf(v0.z, x2, acc0);
        acc0 = fmaf(v0.w, x3, acc0);
        if (has1) {
          float4 v1 = *(const float4*)(w1 + j);
          acc1 = fmaf(v1.x, x0, acc1);
          acc1 = fmaf(v1.y, x1, acc1);
          acc1 = fmaf(v1.z, x2, acc1);
          acc1 = fmaf(v1.w, x3, acc1);
        }
      }
    }

    hbuf[o0] = fast_sigmoid(acc0 + b1[o0]);
    if (has1) hbuf[o1] = fast_sigmoid(acc1 + b1[o1]);
    __syncthreads();

    {  // layer 2
      float a0 = b2[o0], a1 = has1 ? b2[o1] : 0.0f;
      const float* w0r = W2 + o0 * 100;
      const float* w1r = W2 + o1 * 100;
      for (int k = 0; k < 100; ++k) {
        float hv = hbuf[k];
        a0 = fmaf(w0r[k], hv, a0);
        if (has1) a1 = fmaf(w1r[k], hv, a1);
      }
      hbuf2[o0] = fast_sigmoid(a0);
      if (has1) hbuf2[o1] = fast_sigmoid(a1);
    }
    __syncthreads();

    {  // layer 3 (relu)
      float a0 = b3[o0], a1 = has1 ? b3[o1] : 0.0f;
      const float* w0r = W3 + o0 * 100;
      const float* w1r = W3 + o1 * 100;
      for (int k = 0; k < 100; ++k) {
        float hv = hbuf2[k];
        a0 = fmaf(w0r[k], hv, a0);
        if (has1) a1 = fmaf(w1r[k], hv, a1);
      }
      hbuf[o0] = fmaxf(a0, 0.0f);
      if (has1) hbuf[o1] = fmaxf(a1, 0.0f);
    }
    __syncthreads();

    float r = hbuf[o0] * W4[o0] + (has1 ? hbuf[o1] * W4[o1] : 0.0f);
    r = wave_sum_uniform(r);
    if (lane == 0) out[b] = r + b4[0];
  }
}

extern "C" void kernel_launch(void* const* d_in, const int* in_sizes, int n_in,
                              void* d_out, int out_size, void* d_ws, size_t ws_size,
                              hipStream_t stream) {
  const float* x   = (const float*)d_in[0];
  const float* Wih = (const float*)d_in[1];
  const float* Whh = (const float*)d_in[2];
  const float* bih = (const float*)d_in[3];
  const float* bhh = (const float*)d_in[4];
  const float* Whr = (const float*)d_in[5];
  const float* W1  = (const float*)d_in[6];
  const float* b1  = (const float*)d_in[7];
  const float* W2  = (const float*)d_in[8];
  const float* b2  = (const float*)d_in[9];
  const float* W3  = (const float*)d_in[10];
  const float* b3  = (const float*)d_in[11];
  const float* W4  = (const float*)d_in[12];
  const float* b4  = (const float*)d_in[13];

  float* seq   = (float*)d_ws;                       // [5][128][1000] f32 = 2.56 MB
  int*   flags = (int*)(seq + LAYERS * BATCH * TT);  // [5][128] int

  hipMemsetAsync(flags, 0, LAYERS * BATCH * sizeof(int), stream);
  fused_pipeline_kernel<<<LAYERS * BATCH + BATCH, 64, 0, stream>>>(
      x, Wih, Whh, bih, bhh, Whr, W1, b1, W2, b2, W3, b3, W4, b4,
      seq, flags, (float*)d_out);
}

// Round 9
// 748.300 us; speedup vs baseline: 1.1016x; 1.1016x over previous
//
#include <hip/hip_runtime.h>

// voltageNN: 5-layer projected LSTM (H=256, P=1) over T=1000, B=128 + MLP head.
// R9: R5 dataflow (one wave per (layer,batch), agent-scope flag pipeline,
// fused MLP-head stage) with ONE change: all per-lane LSTM state is held in
// 56 INDIVIDUALLY NAMED scalar floats (no arrays, no lambdas).
// Rationale: VGPR_Count was 32-44 in ALL prior rounds while the algorithm
// needs 56 persistent floats/lane -> the weight arrays were living in
// scratch, reloaded every step (~200 cyc latency bursts = the invariant
// ~700 cyc/step stall; VALUBusy pinned at 35%; launch_bounds no-op).
// Named scalars + launch_bounds(64,1) force them into VGPRs.
// Gate: VGPR_Count >= 96, else theory dead -> inline asm next.

#define LAYERS 5
#define TT 1000
#define BATCH 128
#define CH 40            // chunk length (divides TT; <= 64)
#define NCH (TT / CH)    // 25 chunks

#define LOG2E 1.4426950408889634f
#define NLOG2E (-1.4426950408889634f)
#define N2LOG2E (-2.8853900817779268f)

__device__ __forceinline__ float fast_exp2(float x) {
#if __has_builtin(__builtin_amdgcn_exp2f)
  return __builtin_amdgcn_exp2f(x);
#else
  return __exp2f(x);
#endif
}
__device__ __forceinline__ float fast_rcp(float x) {
#if __has_builtin(__builtin_amdgcn_rcpf)
  return __builtin_amdgcn_rcpf(x);
#else
  return 1.0f / x;
#endif
}
__device__ __forceinline__ float fast_sigmoid(float z) {
  float e = fast_exp2(NLOG2E * z);
  return fast_rcp(1.0f + e);
}

template <int CTRL>
__device__ __forceinline__ float dpp_add(float v) {
  int moved = __builtin_amdgcn_update_dpp(0, __builtin_bit_cast(int, v),
                                          CTRL, 0xF, 0xF, false);
  return v + __builtin_bit_cast(float, moved);
}

// Wave64 total -> wave-uniform (readlane 63). Verified absmax==0 since R4.
__device__ __forceinline__ float wave_sum_uniform(float v) {
  v = dpp_add<0x128>(v);  // row_ror:8
  v = dpp_add<0x124>(v);  // row_ror:4
  v = dpp_add<0x122>(v);  // row_ror:2
  v = dpp_add<0x121>(v);  // row_ror:1
  v = dpp_add<0x142>(v);  // row_bcast:15
  v = dpp_add<0x143>(v);  // row_bcast:31
  return __builtin_bit_cast(float, __builtin_amdgcn_readlane(__builtin_bit_cast(int, v), 63));
}

__device__ __forceinline__ float lane_bcast(float v, int s) {
  return __builtin_bit_cast(float, __builtin_amdgcn_readlane(__builtin_bit_cast(int, v), s));
}

// ---- named-scalar weight load (g = gate, k = unit group, SC = exp2-domain scale)
#define LOADW(g, k, SC)                                              \
  const float wix##g##k = Wih[base + g * 256 + k * 64 + lane] * SC;  \
  const float whx##g##k = Whh[base + g * 256 + k * 64 + lane] * SC;  \
  const float gb##g##k  = (bih[base + g * 256 + k * 64 + lane] +     \
                           bhh[base + g * 256 + k * 64 + lane]) * SC;

// all 16 exp2 args + exp2, phase-grouped in source
#define GATE_E(g, k) \
  float e##g##k = fast_exp2(fmaf(h, whx##g##k, fmaf(xs, wix##g##k, gb##g##k)));

// per-unit-group combine: gates -> cell -> projection partial
#define COMBK(k)                                                        \
  float ig##k = fast_rcp(1.0f + e0##k);                                 \
  float fg##k = fast_rcp(1.0f + e1##k);                                 \
  float gg##k = fmaf(2.0f, fast_rcp(1.0f + e2##k), -1.0f);              \
  float og##k = fast_rcp(1.0f + e3##k);                                 \
  cc##k = fmaf(fg##k, cc##k, ig##k * gg##k);                            \
  float tc##k = fmaf(2.0f, fast_rcp(1.0f + fast_exp2(cc##k * N2LOG2E)), -1.0f); \
  float rk##k = og##k * tc##k * whr##k;

__global__ __launch_bounds__(64, 1) void fused_pipeline_kernel(
    const float* __restrict__ x,     // [B, T]
    const float* __restrict__ Wih,   // [L, 1024]
    const float* __restrict__ Whh,   // [L, 1024]
    const float* __restrict__ bih,   // [L, 1024]
    const float* __restrict__ bhh,   // [L, 1024]
    const float* __restrict__ Whr,   // [L, 256]
    const float* __restrict__ W1, const float* __restrict__ b1,
    const float* __restrict__ W2, const float* __restrict__ b2,
    const float* __restrict__ W3, const float* __restrict__ b3,
    const float* __restrict__ W4, const float* __restrict__ b4,
    float* __restrict__ seq,         // [L, B, T] layer outputs (workspace)
    int* __restrict__ flags,         // [L, B] chunk progress counters
    float* __restrict__ out)         // [B]
{
  const int bid  = blockIdx.x;
  const int lane = threadIdx.x & 63;

  if (bid < LAYERS * BATCH) {
    // ------------------------------------------------------------------ LSTM
    const int l = bid >> 7;
    const int b = bid & 127;
    const int base = l * 1024;

    // 48 weight scalars, exp2-domain pre-scaled (i,f,o: -log2e; g: -2log2e)
    LOADW(0, 0, NLOG2E) LOADW(0, 1, NLOG2E) LOADW(0, 2, NLOG2E) LOADW(0, 3, NLOG2E)
    LOADW(1, 0, NLOG2E) LOADW(1, 1, NLOG2E) LOADW(1, 2, NLOG2E) LOADW(1, 3, NLOG2E)
    LOADW(2, 0, N2LOG2E) LOADW(2, 1, N2LOG2E) LOADW(2, 2, N2LOG2E) LOADW(2, 3, N2LOG2E)
    LOADW(3, 0, NLOG2E) LOADW(3, 1, NLOG2E) LOADW(3, 2, NLOG2E) LOADW(3, 3, NLOG2E)

    const float whr0 = Whr[l * 256 + 0 * 64 + lane];
    const float whr1 = Whr[l * 256 + 1 * 64 + lane];
    const float whr2 = Whr[l * 256 + 2 * 64 + lane];
    const float whr3 = Whr[l * 256 + 3 * 64 + lane];
    float cc0 = 0.0f, cc1 = 0.0f, cc2 = 0.0f, cc3 = 0.0f;

    const float* in  = (l == 0) ? (x + b * TT) : (seq + ((l - 1) * BATCH + b) * TT);
    float*      outp = seq + (l * BATCH + b) * TT;
    int*      my_flag = flags + l * BATCH + b;
    const int* in_flag = flags + (l - 1) * BATCH + b;  // used only when l > 0

    float h = 0.0f;
    for (int c = 0; c < NCH; ++c) {
      if (l > 0) {
        while (__hip_atomic_load(in_flag, __ATOMIC_ACQUIRE,
                                 __HIP_MEMORY_SCOPE_AGENT) <= c)
          __builtin_amdgcn_s_sleep(2);
      }
      float xv = 0.0f;
      if (lane < CH) {
        if (l == 0)
          xv = in[c * CH + lane];
        else
          xv = __hip_atomic_load(in + c * CH + lane, __ATOMIC_RELAXED,
                                 __HIP_MEMORY_SCOPE_AGENT);
      }

      float outv = 0.0f;
#pragma unroll 1
      for (int s = 0; s < CH; ++s) {
        const float xs = lane_bcast(xv, s);

        // 16 independent [fmaf|fmaf|exp2] triples, phase-grouped in source
        GATE_E(0, 0) GATE_E(1, 0) GATE_E(2, 0) GATE_E(3, 0)
        GATE_E(0, 1) GATE_E(1, 1) GATE_E(2, 1) GATE_E(3, 1)
        GATE_E(0, 2) GATE_E(1, 2) GATE_E(2, 2) GATE_E(3, 2)
        GATE_E(0, 3) GATE_E(1, 3) GATE_E(2, 3) GATE_E(3, 3)

        COMBK(0) COMBK(1) COMBK(2) COMBK(3)

        float r = (rk0 + rk1) + (rk2 + rk3);
        h = wave_sum_uniform(r);
        if (lane == s) outv = h;
      }

      if (lane < CH)
        __hip_atomic_store(outp + c * CH + lane, outv, __ATOMIC_RELAXED,
                           __HIP_MEMORY_SCOPE_AGENT);
      if (lane == 0)
        __hip_atomic_store(my_flag, c + 1, __ATOMIC_RELEASE,
                           __HIP_MEMORY_SCOPE_AGENT);
    }
  } else {
    // ------------------------------------------------------------- MLP head
    // One wave per batch. Lane owns outputs o0 = lane and o1 = 64+lane (<100).
    __shared__ float hbuf[100];
    __shared__ float hbuf2[100];

    const int b = bid - LAYERS * BATCH;
    const float* h4 = seq + (4 * BATCH + b) * TT;
    const int* f4 = flags + 4 * BATCH + b;
    const int o0 = lane;
    const int o1 = 64 + lane;
    const bool has1 = (o1 < 100);

    float acc0 = 0.0f, acc1 = 0.0f;
    for (int c = 0; c < NCH; ++c) {
      while (__hip_atomic_load(f4, __ATOMIC_ACQUIRE,
                               __HIP_MEMORY_SCOPE_AGENT) <= c)
        __builtin_amdgcn_s_sleep(8);
      float xv = 0.0f;
      if (lane < CH)
        xv = __hip_atomic_load(h4 + c * CH + lane, __ATOMIC_RELAXED,
                               __HIP_MEMORY_SCOPE_AGENT);
      const float* w0 = W1 + o0 * TT + c * CH;   // 160c-byte offset: 16B aligned
      const float* w1 = W1 + o1 * TT + c * CH;
#pragma unroll
      for (int j = 0; j < CH; j += 4) {
        float4 v0 = *(const float4*)(w0 + j);
        float x0 = lane_bcast(xv, j + 0);
        float x1 = lane_bcast(xv, j + 1);
        float x2 = lane_bcast(xv, j + 2);
        float x3 = lane_bcast(xv, j + 3);
        acc0 = fmaf(v0.x, x0, acc0);
        acc0 = fmaf(v0.y, x1, acc0);
        acc0 = fmaf(v0.z, x2, acc0);
        acc0 = fmaf(v0.w, x3, acc0);
        if (has1) {
          float4 v1 = *(const float4*)(w1 + j);
          acc1 = fmaf(v1.x, x0, acc1);
          acc1 = fmaf(v1.y, x1, acc1);
          acc1 = fmaf(v1.z, x2, acc1);
          acc1 = fmaf(v1.w, x3, acc1);
        }
      }
    }

    hbuf[o0] = fast_sigmoid(acc0 + b1[o0]);
    if (has1) hbuf[o1] = fast_sigmoid(acc1 + b1[o1]);
    __syncthreads();

    {  // layer 2
      float a0 = b2[o0], a1 = has1 ? b2[o1] : 0.0f;
      const float* w0r = W2 + o0 * 100;
      const float* w1r = W2 + o1 * 100;
      for (int k = 0; k < 100; ++k) {
        float hv = hbuf[k];
        a0 = fmaf(w0r[k], hv, a0);
        if (has1) a1 = fmaf(w1r[k], hv, a1);
      }
      hbuf2[o0] = fast_sigmoid(a0);
      if (has1) hbuf2[o1] = fast_sigmoid(a1);
    }
    __syncthreads();

    {  // layer 3 (relu)
      float a0 = b3[o0], a1 = has1 ? b3[o1] : 0.0f;
      const float* w0r = W3 + o0 * 100;
      const float* w1r = W3 + o1 * 100;
      for (int k = 0; k < 100; ++k) {
        float hv = hbuf2[k];
        a0 = fmaf(w0r[k], hv, a0);
        if (has1) a1 = fmaf(w1r[k], hv, a1);
      }
      hbuf[o0] = fmaxf(a0, 0.0f);
      if (has1) hbuf[o1] = fmaxf(a1, 0.0f);
    }
    __syncthreads();

    float r = hbuf[o0] * W4[o0] + (has1 ? hbuf[o1] * W4[o1] : 0.0f);
    r = wave_sum_uniform(r);
    if (lane == 0) out[b] = r + b4[0];
  }
}

extern "C" void kernel_launch(void* const* d_in, const int* in_sizes, int n_in,
                              void* d_out, int out_size, void* d_ws, size_t ws_size,
                              hipStream_t stream) {
  const float* x   = (const float*)d_in[0];
  const float* Wih = (const float*)d_in[1];
  const float* Whh = (const float*)d_in[2];
  const float* bih = (const float*)d_in[3];
  const float* bhh = (const float*)d_in[4];
  const float* Whr = (const float*)d_in[5];
  const float* W1  = (const float*)d_in[6];
  const float* b1  = (const float*)d_in[7];
  const float* W2  = (const float*)d_in[8];
  const float* b2  = (const float*)d_in[9];
  const float* W3  = (const float*)d_in[10];
  const float* b3  = (const float*)d_in[11];
  const float* W4  = (const float*)d_in[12];
  const float* b4  = (const float*)d_in[13];

  float* seq   = (float*)d_ws;                       // [5][128][1000] f32 = 2.56 MB
  int*   flags = (int*)(seq + LAYERS * BATCH * TT);  // [5][128] int

  hipMemsetAsync(flags, 0, LAYERS * BATCH * sizeof(int), stream);
  fused_pipeline_kernel<<<LAYERS * BATCH + BATCH, 64, 0, stream>>>(
      x, Wih, Whh, bih, bhh, Whr, W1, b1, W2, b2, W3, b3, W4, b4,
      seq, flags, (float*)d_out);
}